// Round 7
// baseline (447.469 us; speedup 1.0000x reference)
//
#include <hip/hip_runtime.h>
#include <stdint.h>

typedef __attribute__((ext_vector_type(8))) short short8;
typedef __attribute__((ext_vector_type(4))) float floatx4;

__device__ __forceinline__ unsigned short f2bf(float f) {
    unsigned u = __float_as_uint(f);
    u += 0x7FFFu + ((u >> 16) & 1u);
    return (unsigned short)(u >> 16);
}

__device__ __forceinline__ void gload_lds16(const void* g, void* l) {
    __builtin_amdgcn_global_load_lds(
        (const __attribute__((address_space(1))) unsigned int*)g,
        (__attribute__((address_space(3))) unsigned int*)l, 16, 0, 0);
}

// ---- prep: X fp32 -> bf16 (same layout) ----
__global__ __launch_bounds__(256)
void conv_x(const float* __restrict__ x, unsigned short* __restrict__ xb) {
    const size_t total = (size_t)16384 * 1024;
    for (size_t i = ((size_t)blockIdx.x * 256 + threadIdx.x) * 8; i < total;
         i += (size_t)2048 * 256 * 8) {
        float4 a = *(const float4*)&x[i];
        float4 b = *(const float4*)&x[i + 4];
        uint4 o;
        o.x = f2bf(a.x) | ((unsigned)f2bf(a.y) << 16);
        o.y = f2bf(a.z) | ((unsigned)f2bf(a.w) << 16);
        o.z = f2bf(b.x) | ((unsigned)f2bf(b.y) << 16);
        o.w = f2bf(b.z) | ((unsigned)f2bf(b.w) << 16);
        *(uint4*)&xb[i] = o;
    }
}

// ---- prep: transpose all three W into one Wt[1152][1024] bf16 ----
__global__ __launch_bounds__(256)
void transpose_all(const float* __restrict__ Wv, const float* __restrict__ Wq,
                   const float* __restrict__ Wk, unsigned short* __restrict__ Wt) {
    __shared__ float T[64][65];
    const int t = threadIdx.x;
    const int k0 = blockIdx.x * 64;
    const int y = blockIdx.y;
    const float* src; int N, n0, rowoff;
    if (y < 16)      { src = Wv; N = 1024; n0 = y * 64; rowoff = 0; }
    else if (y == 16){ src = Wq; N = 64;   n0 = 0;      rowoff = 1024; }
    else             { src = Wk; N = 64;   n0 = 0;      rowoff = 1088; }
    const int r = t >> 4, c4 = (t & 15) * 4;
#pragma unroll
    for (int i = 0; i < 4; i++) {
        float4 v = *(const float4*)&src[(size_t)(k0 + r + 16 * i) * N + n0 + c4];
        T[r + 16 * i][c4] = v.x; T[r + 16 * i][c4 + 1] = v.y;
        T[r + 16 * i][c4 + 2] = v.z; T[r + 16 * i][c4 + 3] = v.w;
    }
    __syncthreads();
#pragma unroll
    for (int i = 0; i < 4; i++) {
        const int n = rowoff + n0 + r + 16 * i;
        unsigned short b0 = f2bf(T[c4 + 0][r + 16 * i]);
        unsigned short b1 = f2bf(T[c4 + 1][r + 16 * i]);
        unsigned short b2 = f2bf(T[c4 + 2][r + 16 * i]);
        unsigned short b3 = f2bf(T[c4 + 3][r + 16 * i]);
        uint2 pv;
        pv.x = b0 | ((unsigned)b1 << 16);
        pv.y = b2 | ((unsigned)b3 << 16);
        *(uint2*)&Wt[(size_t)n * 1024 + k0 + c4] = pv;
    }
}

// ---- prep: pack [bv | bq | bk] into bfull[1152] ----
__global__ __launch_bounds__(576)
void pack_bias_all(const float* __restrict__ bv, const float* __restrict__ bq,
                   const float* __restrict__ bk, float* __restrict__ bf) {
    const int t = blockIdx.x * 576 + threadIdx.x;
    if (t < 1024) bf[t] = bv[t];
    else if (t < 1088) bf[t] = bq[t - 1024];
    else if (t < 1152) bf[t] = bk[t - 1088];
}

// ---- fused m97-style 128x128 bf16 GEMM over N=1152 = [V(1024) | QK(128)] ----
__global__ __launch_bounds__(256)
void gemm_fused(const unsigned short* __restrict__ A,
                const unsigned short* __restrict__ Bt,
                const float* __restrict__ bias,
                unsigned short* __restrict__ Vt,
                unsigned short* __restrict__ QKb)
{
    __shared__ unsigned short As[128 * 32];
    __shared__ unsigned short Bs[128 * 32];
    const int tid = threadIdx.x;
    const int w = tid >> 6, l = tid & 63;
    const int quad = l >> 4, l16 = l & 15;
    const int wr = w >> 1, wc = w & 1;
    const int m0 = blockIdx.x * 128, n0 = blockIdx.y * 128;

    const int lr = l >> 2, lk = (l & 3) * 8;
    const unsigned short* Ag0 = A + (size_t)(m0 + w * 16 + lr) * 1024 + lk;
    const unsigned short* Ag1 = Ag0 + (size_t)64 * 1024;
    const unsigned short* Bg0 = Bt + (size_t)(n0 + w * 16 + lr) * 1024 + lk;
    const unsigned short* Bg1 = Bg0 + (size_t)64 * 1024;
    unsigned short* Al0 = &As[w * 512 + l * 8];
    unsigned short* Bl0 = &Bs[w * 512 + l * 8];

    floatx4 acc[4][4];
#pragma unroll
    for (int i = 0; i < 4; i++)
#pragma unroll
        for (int j = 0; j < 4; j++) acc[i][j] = (floatx4)0.f;

    for (int e0 = 0; e0 < 1024; e0 += 32) {
        gload_lds16(Ag0 + e0, Al0);
        gload_lds16(Ag1 + e0, Al0 + 2048);
        gload_lds16(Bg0 + e0, Bl0);
        gload_lds16(Bg1 + e0, Bl0 + 2048);
        __syncthreads();
        short8 af[4], bf[4];
#pragma unroll
        for (int i = 0; i < 4; i++)
            af[i] = *(const short8*)&As[(wr * 64 + i * 16 + l16) * 32 + quad * 8];
#pragma unroll
        for (int j = 0; j < 4; j++)
            bf[j] = *(const short8*)&Bs[(wc * 64 + j * 16 + l16) * 32 + quad * 8];
#pragma unroll
        for (int i = 0; i < 4; i++)
#pragma unroll
            for (int j = 0; j < 4; j++)
                acc[i][j] = __builtin_amdgcn_mfma_f32_16x16x32_bf16(af[i], bf[j], acc[i][j], 0, 0, 0);
        __syncthreads();
    }

    const bool toQK = (n0 >= 1024);
#pragma unroll
    for (int j = 0; j < 4; j++) {
        const int n = n0 + wc * 64 + j * 16 + l16;
        const float bn = bias[n];
#pragma unroll
        for (int i = 0; i < 4; i++) {
            const int mb = m0 + wr * 64 + i * 16 + quad * 4;
            if (!toQK) {
                unsigned short t[4];
#pragma unroll
                for (int r = 0; r < 4; r++) t[r] = f2bf(acc[i][j][r] + bn);
                uint2 pv;
                pv.x = t[0] | ((unsigned)t[1] << 16);
                pv.y = t[2] | ((unsigned)t[3] << 16);
                *(uint2*)&Vt[(size_t)n * 16384 + mb] = pv;
            } else {
#pragma unroll
                for (int r = 0; r < 4; r++)
                    QKb[(size_t)(mb + r) * 128 + (n - 1024)] = f2bf(acc[i][j][r] + bn);
            }
        }
    }
}

// ---- attention v9: verified v5 loop body, split-K for long blocks.
//      qt<32: one block, full range, normalize directly (identical to v5).
//      qt>=32: h0 covers k in [0,2048) -> unnormalized A0 into out + L0;
//              h1 covers k in [2048, q0+64) -> A1 (fp32, ws) + L1.
//      combine kernel merges rows >= 2048. Max serial iters: 128 -> 64.
__global__ __launch_bounds__(512, 4)
void attn_fused(const unsigned short* __restrict__ QKb, // 16384 x 128 bf16 (Q|K)
                const unsigned short* __restrict__ Vt,  // 1024 x 16384 bf16 (dv, bs)
                const float* __restrict__ maskx,        // 4 x 4096
                float* __restrict__ out,                // 4 x 4096 x 1024
                float* __restrict__ A1,                 // 4 x 2048 x 1024 (rows>=2048)
                float* __restrict__ L0,
                float* __restrict__ L1)
{
    __shared__ unsigned short Qs[64 * 72];
    __shared__ unsigned short Ps[2][64 * 40];
    __shared__ float Ls[64];

    const int tid = threadIdx.x;
    const int wave = tid >> 6, lane = tid & 63;
    const int quad = lane >> 4, l16 = lane & 15;
    const int bid = blockIdx.x;
    // bid&7 = (b,dvh): same combo -> same XCD slot under round-robin dispatch
    const int dvh = bid & 1;
    const int b = (bid >> 1) & 3;
    const int t = bid >> 3;                 // 0..95
    const int h = (t < 64) ? 0 : 1;
    const int qt = (t < 32) ? (63 - t) : (t < 64) ? (t - 32) : (127 - t); // h1: qt 32..63
    const int q0 = qt * 64;
    const int gq0 = b * 4096 + q0;
    const int klo = h ? 2048 : 0;
    const int khi = h ? (q0 + 64) : ((q0 + 64 < 2048) ? (q0 + 64) : 2048);
    const int niter = (khi - klo) >> 5;

    if (tid < 64) Ls[tid] = 0.f;
    {
        const int r = tid >> 3, c = (tid & 7) * 8;
        uint4 v = *(const uint4*)&QKb[(size_t)(gq0 + r) * 128 + c];
        *(uint4*)&Qs[r * 72 + c] = v;
    }
    __syncthreads();

    const int rb = wave >> 1;   // S-phase row block 0..3
    const int kb = wave & 1;    // S-phase key sub-block 0..1
    bool pq[4];
#pragma unroll
    for (int r = 0; r < 4; r++)
        pq[r] = maskx[b * 4096 + q0 + rb * 16 + quad * 4 + r] < -1e30f;

    const short8 qa0 = *(const short8*)&Qs[(rb * 16 + l16) * 72 + quad * 8];
    const short8 qa1 = *(const short8*)&Qs[(rb * 16 + l16) * 72 + 32 + quad * 8];

    floatx4 acc[4][4];
#pragma unroll
    for (int i = 0; i < 4; i++)
#pragma unroll
        for (int j = 0; j < 4; j++) acc[i][j] = (floatx4)0.f;
    float lacc[4] = {0.f, 0.f, 0.f, 0.f};

    const float scale = 0.125f;
    const int dv0 = dvh * 512 + wave * 64;

    // per-lane bases (offset by klo)
    const unsigned short* kptr = QKb + ((size_t)(b * 4096 + klo + kb * 16 + l16) * 128 + 64 + quad * 8);
    size_t voff[4];
#pragma unroll
    for (int cb = 0; cb < 4; cb++)
        voff[cb] = (size_t)(dv0 + cb * 16 + l16) * 16384 + b * 4096 + quad * 8;

    // prefetch for iter 0: K fragments + mask value
    short8 kc0 = *(const short8*)kptr;
    short8 kc1 = *(const short8*)(kptr + 32);
    float mval = maskx[b * 4096 + klo + kb * 16 + l16];

    for (int kt = 0; kt < niter; kt++) {
        const int k0 = klo + kt * 32;
        // V loads for THIS iter issued first (consumed after the barrier)
        short8 vb[4];
#pragma unroll
        for (int cb = 0; cb < 4; cb++)
            vb[cb] = *(const short8*)&Vt[voff[cb] + k0];
        // S = Q K^T using prefetched K
        floatx4 s = (floatx4)0.f;
        s = __builtin_amdgcn_mfma_f32_16x16x32_bf16(qa0, kc0, s, 0, 0, 0);
        s = __builtin_amdgcn_mfma_f32_16x16x32_bf16(qa1, kc1, s, 0, 0, 0);
        // prefetch K + mask for next iter (clamped to stay in-bounds);
        // these stay in flight across the relaxed barrier below
        const bool pk = mval < -1e30f;
        {
            int kn = k0 + 32 + kb * 16 + l16;
            if (kn > 4095) kn = 4095;
            const unsigned short* np = QKb + ((size_t)(b * 4096 + kn) * 128 + 64 + quad * 8);
            kc0 = *(const short8*)np;
            kc1 = *(const short8*)(np + 32);
            mval = maskx[b * 4096 + kn];
        }
        const int kg = k0 + kb * 16 + l16;
        unsigned short pbits[4];
#pragma unroll
        for (int r = 0; r < 4; r++) {
            const int qrow = q0 + rb * 16 + quad * 4 + r;
            float p = 0.f;
            if (kg <= qrow && pk == pq[r]) p = __expf(s[r] * scale);
            lacc[r] += p;
            pbits[r] = f2bf(p);
        }
        // write P (double-buffered), then lgkm-only barrier: global loads stay in flight
        unsigned short* Pw = Ps[kt & 1];
#pragma unroll
        for (int r = 0; r < 4; r++)
            Pw[(rb * 16 + quad * 4 + r) * 40 + kb * 16 + l16] = pbits[r];
        asm volatile("s_waitcnt lgkmcnt(0)" ::: "memory");
        __builtin_amdgcn_s_barrier();
        __builtin_amdgcn_sched_barrier(0);
        const unsigned short* Pr = Ps[kt & 1];
        short8 pa[4];
#pragma unroll
        for (int r2 = 0; r2 < 4; r2++)
            pa[r2] = *(const short8*)&Pr[(r2 * 16 + l16) * 40 + quad * 8];
#pragma unroll
        for (int cb = 0; cb < 4; cb++)
#pragma unroll
            for (int r2 = 0; r2 < 4; r2++)
                acc[r2][cb] = __builtin_amdgcn_mfma_f32_16x16x32_bf16(pa[r2], vb[cb], acc[r2][cb], 0, 0, 0);
    }

#pragma unroll
    for (int r = 0; r < 4; r++) {
        float v = lacc[r];
        v += __shfl_xor(v, 1);
        v += __shfl_xor(v, 2);
        v += __shfl_xor(v, 4);
        v += __shfl_xor(v, 8);
        if (l16 == 0) atomicAdd(&Ls[rb * 16 + quad * 4 + r], v);
    }
    __syncthreads();

    if (qt < 32) {
        // full range handled here: normalize and write final
#pragma unroll
        for (int r2 = 0; r2 < 4; r2++) {
#pragma unroll
            for (int r = 0; r < 4; r++) {
                const int qrow = q0 + r2 * 16 + quad * 4 + r;
                const float inv = 1.f / Ls[r2 * 16 + quad * 4 + r];
#pragma unroll
                for (int cb = 0; cb < 4; cb++)
                    out[(size_t)(b * 4096 + qrow) * 1024 + dv0 + cb * 16 + l16] = acc[r2][cb][r] * inv;
            }
        }
    } else if (h == 0) {
        // partial A0 (unnormalized) into out; L0 for combine
#pragma unroll
        for (int r2 = 0; r2 < 4; r2++)
#pragma unroll
            for (int r = 0; r < 4; r++) {
                const int qrow = q0 + r2 * 16 + quad * 4 + r;
#pragma unroll
                for (int cb = 0; cb < 4; cb++)
                    out[(size_t)(b * 4096 + qrow) * 1024 + dv0 + cb * 16 + l16] = acc[r2][cb][r];
            }
        if (dvh == 0 && tid < 64) L0[b * 2048 + q0 - 2048 + tid] = Ls[tid];
    } else {
        // partial A1 (unnormalized) into ws; L1 for combine
#pragma unroll
        for (int r2 = 0; r2 < 4; r2++)
#pragma unroll
            for (int r = 0; r < 4; r++) {
                const int pr = q0 - 2048 + r2 * 16 + quad * 4 + r;
#pragma unroll
                for (int cb = 0; cb < 4; cb++)
                    A1[(size_t)(b * 2048 + pr) * 1024 + dv0 + cb * 16 + l16] = acc[r2][cb][r];
            }
        if (dvh == 0 && tid < 64) L1[b * 2048 + q0 - 2048 + tid] = Ls[tid];
    }
}

// ---- combine: rows >= 2048 per batch: out = (A0 + A1) / (L0 + L1) ----
__global__ __launch_bounds__(256)
void combine(float* __restrict__ out, const float* __restrict__ A1,
             const float* __restrict__ L0, const float* __restrict__ L1) {
    const int wave = threadIdx.x >> 6, lane = threadIdx.x & 63;
    for (int row = blockIdx.x * 4 + wave; row < 4 * 2048; row += gridDim.x * 4) {
        const int b = row >> 11, qr = row & 2047;
        const float inv = 1.f / (L0[row] + L1[row]);
        float4* po = (float4*)&out[(size_t)(b * 4096 + 2048 + qr) * 1024];
        const float4* pa = (const float4*)&A1[(size_t)row * 1024];
        for (int c = lane; c < 256; c += 64) {
            float4 o = po[c];
            const float4 a = pa[c];
            o.x = (o.x + a.x) * inv;
            o.y = (o.y + a.y) * inv;
            o.z = (o.z + a.z) * inv;
            o.w = (o.w + a.w) * inv;
            po[c] = o;
        }
    }
}

extern "C" void kernel_launch(void* const* d_in, const int* in_sizes, int n_in,
                              void* d_out, int out_size, void* d_ws, size_t ws_size,
                              hipStream_t stream) {
    const float* x  = (const float*)d_in[0];
    const float* Wq = (const float*)d_in[1];
    const float* bq = (const float*)d_in[2];
    const float* Wk = (const float*)d_in[3];
    const float* bk = (const float*)d_in[4];
    const float* Wv = (const float*)d_in[5];
    const float* bv = (const float*)d_in[6];
    const float* mk = (const float*)d_in[7];
    float* out = (float*)d_out;

    char* ws = (char*)d_ws;
    unsigned short* Xb   = (unsigned short*)ws;                      // 32 MB (reused as A1)
    unsigned short* Vt   = (unsigned short*)(ws + (33554432));       // 32 MB (1024 x 16384)
    unsigned short* Wt   = (unsigned short*)(ws + (67108864));       // 2.25 MB (1152 x 1024)
    unsigned short* QKb  = (unsigned short*)(ws + (69468160));       // 4 MB  (16384 x 128)
    float*          bfull= (float*)(ws + (73662464));                // 4.5 KB
    float*          L0   = (float*)(ws + (73667072));                // 32 KB
    float*          L1   = (float*)(ws + (73699840));                // 32 KB
    float*          A1   = (float*)ws;                               // aliases Xb (free post-GEMM)

    conv_x<<<2048, 256, 0, stream>>>(x, Xb);
    transpose_all<<<dim3(16, 18), 256, 0, stream>>>(Wv, Wq, Wk, Wt);
    pack_bias_all<<<2, 576, 0, stream>>>(bv, bq, bk, bfull);

    gemm_fused<<<dim3(128, 9), 256, 0, stream>>>(Xb, Wt, bfull, Vt, QKb);

    attn_fused<<<dim3(4 * 96 * 2), 512, 0, stream>>>(QKb, Vt, mk, out, A1, L0, L1);
    combine<<<512, 256, 0, stream>>>(out, A1, L0, L1);
}

// Round 8
// 394.097 us; speedup vs baseline: 1.1354x; 1.1354x over previous
//
#include <hip/hip_runtime.h>
#include <stdint.h>

typedef __attribute__((ext_vector_type(8))) short short8;
typedef __attribute__((ext_vector_type(4))) float floatx4;

__device__ __forceinline__ unsigned short f2bf(float f) {
    unsigned u = __float_as_uint(f);
    u += 0x7FFFu + ((u >> 16) & 1u);
    return (unsigned short)(u >> 16);
}

__device__ __forceinline__ void gload_lds16(const void* g, void* l) {
    __builtin_amdgcn_global_load_lds(
        (const __attribute__((address_space(1))) unsigned int*)g,
        (__attribute__((address_space(3))) unsigned int*)l, 16, 0, 0);
}

// ---- prep: X fp32 -> bf16 (same layout) ----
__global__ __launch_bounds__(256)
void conv_x(const float* __restrict__ x, unsigned short* __restrict__ xb) {
    const size_t total = (size_t)16384 * 1024;
    for (size_t i = ((size_t)blockIdx.x * 256 + threadIdx.x) * 8; i < total;
         i += (size_t)2048 * 256 * 8) {
        float4 a = *(const float4*)&x[i];
        float4 b = *(const float4*)&x[i + 4];
        uint4 o;
        o.x = f2bf(a.x) | ((unsigned)f2bf(a.y) << 16);
        o.y = f2bf(a.z) | ((unsigned)f2bf(a.w) << 16);
        o.z = f2bf(b.x) | ((unsigned)f2bf(b.y) << 16);
        o.w = f2bf(b.z) | ((unsigned)f2bf(b.w) << 16);
        *(uint4*)&xb[i] = o;
    }
}

// ---- prep: transpose all three W into one Wt[1152][1024] bf16 ----
__global__ __launch_bounds__(256)
void transpose_all(const float* __restrict__ Wv, const float* __restrict__ Wq,
                   const float* __restrict__ Wk, unsigned short* __restrict__ Wt) {
    __shared__ float T[64][65];
    const int t = threadIdx.x;
    const int k0 = blockIdx.x * 64;
    const int y = blockIdx.y;
    const float* src; int N, n0, rowoff;
    if (y < 16)      { src = Wv; N = 1024; n0 = y * 64; rowoff = 0; }
    else if (y == 16){ src = Wq; N = 64;   n0 = 0;      rowoff = 1024; }
    else             { src = Wk; N = 64;   n0 = 0;      rowoff = 1088; }
    const int r = t >> 4, c4 = (t & 15) * 4;
#pragma unroll
    for (int i = 0; i < 4; i++) {
        float4 v = *(const float4*)&src[(size_t)(k0 + r + 16 * i) * N + n0 + c4];
        T[r + 16 * i][c4] = v.x; T[r + 16 * i][c4 + 1] = v.y;
        T[r + 16 * i][c4 + 2] = v.z; T[r + 16 * i][c4 + 3] = v.w;
    }
    __syncthreads();
#pragma unroll
    for (int i = 0; i < 4; i++) {
        const int n = rowoff + n0 + r + 16 * i;
        unsigned short b0 = f2bf(T[c4 + 0][r + 16 * i]);
        unsigned short b1 = f2bf(T[c4 + 1][r + 16 * i]);
        unsigned short b2 = f2bf(T[c4 + 2][r + 16 * i]);
        unsigned short b3 = f2bf(T[c4 + 3][r + 16 * i]);
        uint2 pv;
        pv.x = b0 | ((unsigned)b1 << 16);
        pv.y = b2 | ((unsigned)b3 << 16);
        *(uint2*)&Wt[(size_t)n * 1024 + k0 + c4] = pv;
    }
}

// ---- prep: pack [bv | bq | bk] into bfull[1152] ----
__global__ __launch_bounds__(576)
void pack_bias_all(const float* __restrict__ bv, const float* __restrict__ bq,
                   const float* __restrict__ bk, float* __restrict__ bf) {
    const int t = blockIdx.x * 576 + threadIdx.x;
    if (t < 1024) bf[t] = bv[t];
    else if (t < 1088) bf[t] = bq[t - 1024];
    else if (t < 1152) bf[t] = bk[t - 1088];
}

// ---- fused m97-style 128x128 bf16 GEMM over N=1152 = [V(1024) | QK(128)] ----
__global__ __launch_bounds__(256)
void gemm_fused(const unsigned short* __restrict__ A,
                const unsigned short* __restrict__ Bt,
                const float* __restrict__ bias,
                unsigned short* __restrict__ Vt,
                unsigned short* __restrict__ QKb)
{
    __shared__ unsigned short As[128 * 32];
    __shared__ unsigned short Bs[128 * 32];
    const int tid = threadIdx.x;
    const int w = tid >> 6, l = tid & 63;
    const int quad = l >> 4, l16 = l & 15;
    const int wr = w >> 1, wc = w & 1;
    const int m0 = blockIdx.x * 128, n0 = blockIdx.y * 128;

    const int lr = l >> 2, lk = (l & 3) * 8;
    const unsigned short* Ag0 = A + (size_t)(m0 + w * 16 + lr) * 1024 + lk;
    const unsigned short* Ag1 = Ag0 + (size_t)64 * 1024;
    const unsigned short* Bg0 = Bt + (size_t)(n0 + w * 16 + lr) * 1024 + lk;
    const unsigned short* Bg1 = Bg0 + (size_t)64 * 1024;
    unsigned short* Al0 = &As[w * 512 + l * 8];
    unsigned short* Bl0 = &Bs[w * 512 + l * 8];

    floatx4 acc[4][4];
#pragma unroll
    for (int i = 0; i < 4; i++)
#pragma unroll
        for (int j = 0; j < 4; j++) acc[i][j] = (floatx4)0.f;

    for (int e0 = 0; e0 < 1024; e0 += 32) {
        gload_lds16(Ag0 + e0, Al0);
        gload_lds16(Ag1 + e0, Al0 + 2048);
        gload_lds16(Bg0 + e0, Bl0);
        gload_lds16(Bg1 + e0, Bl0 + 2048);
        __syncthreads();
        short8 af[4], bf[4];
#pragma unroll
        for (int i = 0; i < 4; i++)
            af[i] = *(const short8*)&As[(wr * 64 + i * 16 + l16) * 32 + quad * 8];
#pragma unroll
        for (int j = 0; j < 4; j++)
            bf[j] = *(const short8*)&Bs[(wc * 64 + j * 16 + l16) * 32 + quad * 8];
#pragma unroll
        for (int i = 0; i < 4; i++)
#pragma unroll
            for (int j = 0; j < 4; j++)
                acc[i][j] = __builtin_amdgcn_mfma_f32_16x16x32_bf16(af[i], bf[j], acc[i][j], 0, 0, 0);
        __syncthreads();
    }

    const bool toQK = (n0 >= 1024);
#pragma unroll
    for (int j = 0; j < 4; j++) {
        const int n = n0 + wc * 64 + j * 16 + l16;
        const float bn = bias[n];
#pragma unroll
        for (int i = 0; i < 4; i++) {
            const int mb = m0 + wr * 64 + i * 16 + quad * 4;
            if (!toQK) {
                unsigned short t[4];
#pragma unroll
                for (int r = 0; r < 4; r++) t[r] = f2bf(acc[i][j][r] + bn);
                uint2 pv;
                pv.x = t[0] | ((unsigned)t[1] << 16);
                pv.y = t[2] | ((unsigned)t[3] << 16);
                *(uint2*)&Vt[(size_t)n * 16384 + mb] = pv;
            } else {
#pragma unroll
                for (int r = 0; r < 4; r++)
                    QKb[(size_t)(mb + r) * 128 + (n - 1024)] = f2bf(acc[i][j][r] + bn);
            }
        }
    }
}

// ---- attention v10: verified v5/round-6 structure; the only change is the
//      V-load position: prologue load + reload right after PV consumes vb,
//      giving a full-iteration prefetch distance at identical register cost.
__global__ __launch_bounds__(512, 4)
void attn_fused(const unsigned short* __restrict__ QKb, // 16384 x 128 bf16 (Q|K)
                const unsigned short* __restrict__ Vt,  // 1024 x 16384 bf16 (dv, bs)
                const float* __restrict__ maskx,        // 4 x 4096
                float* __restrict__ out)                // 4 x 4096 x 1024
{
    __shared__ unsigned short Qs[64 * 72];
    __shared__ unsigned short Ps[2][64 * 40];
    __shared__ float Ls[64];

    const int tid = threadIdx.x;
    const int wave = tid >> 6, lane = tid & 63;
    const int quad = lane >> 4, l16 = lane & 15;
    const int bid = blockIdx.x;
    // bid&7 = (b,dvh): same combo -> same XCD slot under round-robin dispatch
    const int dvh = bid & 1;
    const int b = (bid >> 1) & 3;
    const int t = bid >> 3;                 // 0..63
    const int qt = (t < 32) ? (63 - t) : (t - 32);  // pair sums to 63 per CU
    const int q0 = qt * 64;
    const int gq0 = b * 4096 + q0;

    if (tid < 64) Ls[tid] = 0.f;
    {
        const int r = tid >> 3, c = (tid & 7) * 8;
        uint4 v = *(const uint4*)&QKb[(size_t)(gq0 + r) * 128 + c];
        *(uint4*)&Qs[r * 72 + c] = v;
    }
    __syncthreads();

    const int rb = wave >> 1;   // S-phase row block 0..3
    const int kb = wave & 1;    // S-phase key sub-block 0..1
    bool pq[4];
#pragma unroll
    for (int r = 0; r < 4; r++)
        pq[r] = maskx[b * 4096 + q0 + rb * 16 + quad * 4 + r] < -1e30f;

    const short8 qa0 = *(const short8*)&Qs[(rb * 16 + l16) * 72 + quad * 8];
    const short8 qa1 = *(const short8*)&Qs[(rb * 16 + l16) * 72 + 32 + quad * 8];

    floatx4 acc[4][4];
#pragma unroll
    for (int i = 0; i < 4; i++)
#pragma unroll
        for (int j = 0; j < 4; j++) acc[i][j] = (floatx4)0.f;
    float lacc[4] = {0.f, 0.f, 0.f, 0.f};

    const int niter = 2 * qt + 2;
    const float scale = 0.125f;
    const int dv0 = dvh * 512 + wave * 64;

    // per-lane bases
    const unsigned short* kptr = QKb + ((size_t)(b * 4096 + kb * 16 + l16) * 128 + 64 + quad * 8);
    const float* mptr = maskx + b * 4096 + kb * 16 + l16;
    size_t voff[4];
#pragma unroll
    for (int cb = 0; cb < 4; cb++)
        voff[cb] = (size_t)(dv0 + cb * 16 + l16) * 16384 + b * 4096 + quad * 8;

    // prefetch for iter 0: K fragments + mask value + V fragments
    short8 kc0 = *(const short8*)kptr;
    short8 kc1 = *(const short8*)(kptr + 32);
    float mval = *mptr;
    short8 vb[4];
#pragma unroll
    for (int cb = 0; cb < 4; cb++)
        vb[cb] = *(const short8*)&Vt[voff[cb]];

    for (int kt = 0; kt < niter; kt++) {
        const int k0 = kt * 32;
        // S = Q K^T using prefetched K
        floatx4 s = (floatx4)0.f;
        s = __builtin_amdgcn_mfma_f32_16x16x32_bf16(qa0, kc0, s, 0, 0, 0);
        s = __builtin_amdgcn_mfma_f32_16x16x32_bf16(qa1, kc1, s, 0, 0, 0);
        // prefetch K + mask for next iter (clamped to stay in-bounds);
        // these stay in flight across the relaxed barrier below
        const bool pk = mval < -1e30f;
        {
            int kn = k0 + 32 + kb * 16 + l16;
            if (kn > 4095) kn = 4095;
            const unsigned short* np = QKb + ((size_t)(b * 4096 + kn) * 128 + 64 + quad * 8);
            kc0 = *(const short8*)np;
            kc1 = *(const short8*)(np + 32);
            mval = maskx[b * 4096 + kn];
        }
        const int kg = k0 + kb * 16 + l16;
        unsigned short pbits[4];
#pragma unroll
        for (int r = 0; r < 4; r++) {
            const int qrow = q0 + rb * 16 + quad * 4 + r;
            float p = 0.f;
            if (kg <= qrow && pk == pq[r]) p = __expf(s[r] * scale);
            lacc[r] += p;
            pbits[r] = f2bf(p);
        }
        // write P (double-buffered), then lgkm-only barrier: global loads stay in flight
        unsigned short* Pw = Ps[kt & 1];
#pragma unroll
        for (int r = 0; r < 4; r++)
            Pw[(rb * 16 + quad * 4 + r) * 40 + kb * 16 + l16] = pbits[r];
        asm volatile("s_waitcnt lgkmcnt(0)" ::: "memory");
        __builtin_amdgcn_s_barrier();
        __builtin_amdgcn_sched_barrier(0);
        const unsigned short* Pr = Ps[kt & 1];
        short8 pa[4];
#pragma unroll
        for (int r2 = 0; r2 < 4; r2++)
            pa[r2] = *(const short8*)&Pr[(r2 * 16 + l16) * 40 + quad * 8];
#pragma unroll
        for (int cb = 0; cb < 4; cb++)
#pragma unroll
            for (int r2 = 0; r2 < 4; r2++)
                acc[r2][cb] = __builtin_amdgcn_mfma_f32_16x16x32_bf16(pa[r2], vb[cb], acc[r2][cb], 0, 0, 0);
        // V prefetch for NEXT iter, issued right after PV consumed vb:
        // full-iteration cover, same registers (clamp keeps the dead
        // last-iteration prefetch in-bounds)
        {
            const int kv = (k0 + 32 > 4064) ? 4064 : (k0 + 32);
#pragma unroll
            for (int cb = 0; cb < 4; cb++)
                vb[cb] = *(const short8*)&Vt[voff[cb] + kv];
        }
    }

#pragma unroll
    for (int r = 0; r < 4; r++) {
        float v = lacc[r];
        v += __shfl_xor(v, 1);
        v += __shfl_xor(v, 2);
        v += __shfl_xor(v, 4);
        v += __shfl_xor(v, 8);
        if (l16 == 0) atomicAdd(&Ls[rb * 16 + quad * 4 + r], v);
    }
    __syncthreads();

#pragma unroll
    for (int r2 = 0; r2 < 4; r2++) {
#pragma unroll
        for (int r = 0; r < 4; r++) {
            const int qrow = q0 + r2 * 16 + quad * 4 + r;
            const float inv = 1.f / Ls[r2 * 16 + quad * 4 + r];
#pragma unroll
            for (int cb = 0; cb < 4; cb++)
                out[(size_t)(b * 4096 + qrow) * 1024 + dv0 + cb * 16 + l16] = acc[r2][cb][r] * inv;
        }
    }
}

extern "C" void kernel_launch(void* const* d_in, const int* in_sizes, int n_in,
                              void* d_out, int out_size, void* d_ws, size_t ws_size,
                              hipStream_t stream) {
    const float* x  = (const float*)d_in[0];
    const float* Wq = (const float*)d_in[1];
    const float* bq = (const float*)d_in[2];
    const float* Wk = (const float*)d_in[3];
    const float* bk = (const float*)d_in[4];
    const float* Wv = (const float*)d_in[5];
    const float* bv = (const float*)d_in[6];
    const float* mk = (const float*)d_in[7];
    float* out = (float*)d_out;

    char* ws = (char*)d_ws;
    unsigned short* Xb   = (unsigned short*)ws;                      // 32 MB
    unsigned short* Vt   = (unsigned short*)(ws + (33554432));       // 32 MB (1024 x 16384)
    unsigned short* Wt   = (unsigned short*)(ws + (67108864));       // 2.25 MB (1152 x 1024)
    unsigned short* QKb  = (unsigned short*)(ws + (69468160));       // 4 MB  (16384 x 128)
    float*          bfull= (float*)(ws + (73662464));                // 4.5 KB

    conv_x<<<2048, 256, 0, stream>>>(x, Xb);
    transpose_all<<<dim3(16, 18), 256, 0, stream>>>(Wv, Wq, Wk, Wt);
    pack_bias_all<<<2, 576, 0, stream>>>(bv, bq, bk, bfull);

    gemm_fused<<<dim3(128, 9), 256, 0, stream>>>(Xb, Wt, bfull, Vt, QKb);

    attn_fused<<<dim3(4 * 64 * 2), 512, 0, stream>>>(QKb, Vt, mk, out);
}

// Round 10
// 362.572 us; speedup vs baseline: 1.2342x; 1.0869x over previous
//
#include <hip/hip_runtime.h>
#include <stdint.h>

typedef __attribute__((ext_vector_type(8))) short short8;
typedef __attribute__((ext_vector_type(4))) float floatx4;

__device__ __forceinline__ unsigned short f2bf(float f) {
    unsigned u = __float_as_uint(f);
    u += 0x7FFFu + ((u >> 16) & 1u);
    return (unsigned short)(u >> 16);
}

__device__ __forceinline__ void gload_lds16(const void* g, void* l) {
    __builtin_amdgcn_global_load_lds(
        (const __attribute__((address_space(1))) unsigned int*)g,
        (__attribute__((address_space(3))) unsigned int*)l, 16, 0, 0);
}

// ---- prep: X fp32 -> bf16 (same layout) ----
__global__ __launch_bounds__(256)
void conv_x(const float* __restrict__ x, unsigned short* __restrict__ xb) {
    const size_t total = (size_t)16384 * 1024;
    for (size_t i = ((size_t)blockIdx.x * 256 + threadIdx.x) * 8; i < total;
         i += (size_t)2048 * 256 * 8) {
        float4 a = *(const float4*)&x[i];
        float4 b = *(const float4*)&x[i + 4];
        uint4 o;
        o.x = f2bf(a.x) | ((unsigned)f2bf(a.y) << 16);
        o.y = f2bf(a.z) | ((unsigned)f2bf(a.w) << 16);
        o.z = f2bf(b.x) | ((unsigned)f2bf(b.y) << 16);
        o.w = f2bf(b.z) | ((unsigned)f2bf(b.w) << 16);
        *(uint4*)&xb[i] = o;
    }
}

// ---- prep: transpose all three W into one Wt[1152][1024] bf16 ----
__global__ __launch_bounds__(256)
void transpose_all(const float* __restrict__ Wv, const float* __restrict__ Wq,
                   const float* __restrict__ Wk, unsigned short* __restrict__ Wt) {
    __shared__ float T[64][65];
    const int t = threadIdx.x;
    const int k0 = blockIdx.x * 64;
    const int y = blockIdx.y;
    const float* src; int N, n0, rowoff;
    if (y < 16)      { src = Wv; N = 1024; n0 = y * 64; rowoff = 0; }
    else if (y == 16){ src = Wq; N = 64;   n0 = 0;      rowoff = 1024; }
    else             { src = Wk; N = 64;   n0 = 0;      rowoff = 1088; }
    const int r = t >> 4, c4 = (t & 15) * 4;
#pragma unroll
    for (int i = 0; i < 4; i++) {
        float4 v = *(const float4*)&src[(size_t)(k0 + r + 16 * i) * N + n0 + c4];
        T[r + 16 * i][c4] = v.x; T[r + 16 * i][c4 + 1] = v.y;
        T[r + 16 * i][c4 + 2] = v.z; T[r + 16 * i][c4 + 3] = v.w;
    }
    __syncthreads();
#pragma unroll
    for (int i = 0; i < 4; i++) {
        const int n = rowoff + n0 + r + 16 * i;
        unsigned short b0 = f2bf(T[c4 + 0][r + 16 * i]);
        unsigned short b1 = f2bf(T[c4 + 1][r + 16 * i]);
        unsigned short b2 = f2bf(T[c4 + 2][r + 16 * i]);
        unsigned short b3 = f2bf(T[c4 + 3][r + 16 * i]);
        uint2 pv;
        pv.x = b0 | ((unsigned)b1 << 16);
        pv.y = b2 | ((unsigned)b3 << 16);
        *(uint2*)&Wt[(size_t)n * 1024 + k0 + c4] = pv;
    }
}

// ---- prep: pack [bv | bq | bk] into bfull[1152] ----
__global__ __launch_bounds__(576)
void pack_bias_all(const float* __restrict__ bv, const float* __restrict__ bq,
                   const float* __restrict__ bk, float* __restrict__ bf) {
    const int t = blockIdx.x * 576 + threadIdx.x;
    if (t < 1024) bf[t] = bv[t];
    else if (t < 1088) bf[t] = bq[t - 1024];
    else if (t < 1152) bf[t] = bk[t - 1088];
}

// ---- fused m97-style 128x128 bf16 GEMM over N=1152 = [V(1024) | QK(128)] ----
__global__ __launch_bounds__(256)
void gemm_fused(const unsigned short* __restrict__ A,
                const unsigned short* __restrict__ Bt,
                const float* __restrict__ bias,
                unsigned short* __restrict__ Vt,
                unsigned short* __restrict__ QKb)
{
    __shared__ unsigned short As[128 * 32];
    __shared__ unsigned short Bs[128 * 32];
    const int tid = threadIdx.x;
    const int w = tid >> 6, l = tid & 63;
    const int quad = l >> 4, l16 = l & 15;
    const int wr = w >> 1, wc = w & 1;
    const int m0 = blockIdx.x * 128, n0 = blockIdx.y * 128;

    const int lr = l >> 2, lk = (l & 3) * 8;
    const unsigned short* Ag0 = A + (size_t)(m0 + w * 16 + lr) * 1024 + lk;
    const unsigned short* Ag1 = Ag0 + (size_t)64 * 1024;
    const unsigned short* Bg0 = Bt + (size_t)(n0 + w * 16 + lr) * 1024 + lk;
    const unsigned short* Bg1 = Bg0 + (size_t)64 * 1024;
    unsigned short* Al0 = &As[w * 512 + l * 8];
    unsigned short* Bl0 = &Bs[w * 512 + l * 8];

    floatx4 acc[4][4];
#pragma unroll
    for (int i = 0; i < 4; i++)
#pragma unroll
        for (int j = 0; j < 4; j++) acc[i][j] = (floatx4)0.f;

    for (int e0 = 0; e0 < 1024; e0 += 32) {
        gload_lds16(Ag0 + e0, Al0);
        gload_lds16(Ag1 + e0, Al0 + 2048);
        gload_lds16(Bg0 + e0, Bl0);
        gload_lds16(Bg1 + e0, Bl0 + 2048);
        __syncthreads();
        short8 af[4], bf[4];
#pragma unroll
        for (int i = 0; i < 4; i++)
            af[i] = *(const short8*)&As[(wr * 64 + i * 16 + l16) * 32 + quad * 8];
#pragma unroll
        for (int j = 0; j < 4; j++)
            bf[j] = *(const short8*)&Bs[(wc * 64 + j * 16 + l16) * 32 + quad * 8];
#pragma unroll
        for (int i = 0; i < 4; i++)
#pragma unroll
            for (int j = 0; j < 4; j++)
                acc[i][j] = __builtin_amdgcn_mfma_f32_16x16x32_bf16(af[i], bf[j], acc[i][j], 0, 0, 0);
        __syncthreads();
    }

    const bool toQK = (n0 >= 1024);
#pragma unroll
    for (int j = 0; j < 4; j++) {
        const int n = n0 + wc * 64 + j * 16 + l16;
        const float bn = bias[n];
#pragma unroll
        for (int i = 0; i < 4; i++) {
            const int mb = m0 + wr * 64 + i * 16 + quad * 4;
            if (!toQK) {
                unsigned short t[4];
#pragma unroll
                for (int r = 0; r < 4; r++) t[r] = f2bf(acc[i][j][r] + bn);
                uint2 pv;
                pv.x = t[0] | ((unsigned)t[1] << 16);
                pv.y = t[2] | ((unsigned)t[3] << 16);
                *(uint2*)&Vt[(size_t)n * 16384 + mb] = pv;
            } else {
#pragma unroll
                for (int r = 0; r < 4; r++)
                    QKb[(size_t)(mb + r) * 128 + (n - 1024)] = f2bf(acc[i][j][r] + bn);
            }
        }
    }
}

// ---- attention v11: barrier-at-END body rotation. Same waves, same LDS
//      layout, same 2-buffer parity, same barrier count as verified v5 —
//      but PV(kt), S(kt+1) and exp(kt+1) now share one barrier-free region
//      so MFMA/VALU pipes interleave instead of convoying. Phantom last
//      S/exp is auto-masked by the causal test (k0 > q0+63 -> p=0).
__global__ __launch_bounds__(512, 4)
void attn_fused(const unsigned short* __restrict__ QKb, // 16384 x 128 bf16 (Q|K)
                const unsigned short* __restrict__ Vt,  // 1024 x 16384 bf16 (dv, bs)
                const float* __restrict__ maskx,        // 4 x 4096
                float* __restrict__ out)                // 4 x 4096 x 1024
{
    __shared__ unsigned short Qs[64 * 72];
    __shared__ unsigned short Ps[2][64 * 40];
    __shared__ float Ls[64];

    const int tid = threadIdx.x;
    const int wave = tid >> 6, lane = tid & 63;
    const int quad = lane >> 4, l16 = lane & 15;
    const int bid = blockIdx.x;
    const int dvh = bid & 1;
    const int b = (bid >> 1) & 3;
    const int t = bid >> 3;                 // 0..63
    const int qt = (t < 32) ? (63 - t) : (t - 32);  // pair sums to 63 per CU
    const int q0 = qt * 64;
    const int gq0 = b * 4096 + q0;

    if (tid < 64) Ls[tid] = 0.f;
    {
        const int r = tid >> 3, c = (tid & 7) * 8;
        uint4 v = *(const uint4*)&QKb[(size_t)(gq0 + r) * 128 + c];
        *(uint4*)&Qs[r * 72 + c] = v;
    }
    __syncthreads();

    const int rb = wave >> 1;   // S-phase row block 0..3
    const int kb = wave & 1;    // S-phase key sub-block 0..1
    bool pq[4];
#pragma unroll
    for (int r = 0; r < 4; r++)
        pq[r] = maskx[b * 4096 + q0 + rb * 16 + quad * 4 + r] < -1e30f;

    const short8 qa0 = *(const short8*)&Qs[(rb * 16 + l16) * 72 + quad * 8];
    const short8 qa1 = *(const short8*)&Qs[(rb * 16 + l16) * 72 + 32 + quad * 8];

    floatx4 acc[4][4];
#pragma unroll
    for (int i = 0; i < 4; i++)
#pragma unroll
        for (int j = 0; j < 4; j++) acc[i][j] = (floatx4)0.f;
    float lacc[4] = {0.f, 0.f, 0.f, 0.f};

    const int niter = 2 * qt + 2;
    const float scale = 0.125f;
    const int dv0 = dvh * 512 + wave * 64;

    size_t voff[4];
#pragma unroll
    for (int cb = 0; cb < 4; cb++)
        voff[cb] = (size_t)(dv0 + cb * 16 + l16) * 16384 + b * 4096 + quad * 8;

    // ---- prologue: S(0), exp(0), write P[0]; load vb(0) ----
    short8 vb[4];
#pragma unroll
    for (int cb = 0; cb < 4; cb++)
        vb[cb] = *(const short8*)&Vt[voff[cb]];
    {
        const unsigned short* kp = QKb + ((size_t)(b * 4096 + kb * 16 + l16) * 128 + 64 + quad * 8);
        const short8 kc0 = *(const short8*)kp;
        const short8 kc1 = *(const short8*)(kp + 32);
        const float mv = maskx[b * 4096 + kb * 16 + l16];
        floatx4 s = (floatx4)0.f;
        s = __builtin_amdgcn_mfma_f32_16x16x32_bf16(qa0, kc0, s, 0, 0, 0);
        s = __builtin_amdgcn_mfma_f32_16x16x32_bf16(qa1, kc1, s, 0, 0, 0);
        const bool pk = mv < -1e30f;
        const int kg = kb * 16 + l16;
        unsigned short* Pw = Ps[0];
#pragma unroll
        for (int r = 0; r < 4; r++) {
            const int qrow = q0 + rb * 16 + quad * 4 + r;
            float p = 0.f;
            if (kg <= qrow && pk == pq[r]) p = __expf(s[r] * scale);
            lacc[r] += p;
            Pw[(rb * 16 + quad * 4 + r) * 40 + kb * 16 + l16] = f2bf(p);
        }
    }
    asm volatile("s_waitcnt lgkmcnt(0)" ::: "memory");
    __builtin_amdgcn_s_barrier();
    __builtin_amdgcn_sched_barrier(0);

    // ---- main loop: body kt does PV(kt) + S(kt+1) in one region, barrier at end ----
    for (int kt = 0; kt < niter; kt++) {
        const int k0 = kt * 32;
        // K(kt+1) + mask(kt+1) loads issued first (used by S later this body)
        short8 kc0, kc1;
        float mvn;
        {
            int kn = k0 + 32 + kb * 16 + l16;
            if (kn > 4095) kn = 4095;
            const unsigned short* np = QKb + ((size_t)(b * 4096 + kn) * 128 + 64 + quad * 8);
            kc0 = *(const short8*)np;
            kc1 = *(const short8*)(np + 32);
            mvn = maskx[b * 4096 + kn];
        }
        // PV(kt): read P(kt) inline (written last body, barrier'd), consume vb(kt)
        const unsigned short* Pr = Ps[kt & 1];
        __builtin_amdgcn_s_setprio(1);
#pragma unroll
        for (int r2 = 0; r2 < 4; r2++) {
            const short8 pa = *(const short8*)&Pr[(r2 * 16 + l16) * 40 + quad * 8];
#pragma unroll
            for (int cb = 0; cb < 4; cb++)
                acc[r2][cb] = __builtin_amdgcn_mfma_f32_16x16x32_bf16(pa, vb[cb], acc[r2][cb], 0, 0, 0);
        }
        // S(kt+1) — independent of PV, scheduler interleaves
        floatx4 s = (floatx4)0.f;
        s = __builtin_amdgcn_mfma_f32_16x16x32_bf16(qa0, kc0, s, 0, 0, 0);
        s = __builtin_amdgcn_mfma_f32_16x16x32_bf16(qa1, kc1, s, 0, 0, 0);
        __builtin_amdgcn_s_setprio(0);
        // vb(kt+1) prefetch (register reuse; clamp keeps dead last load in-bounds)
        {
            const int kv = (k0 + 32 > 4064) ? 4064 : (k0 + 32);
#pragma unroll
            for (int cb = 0; cb < 4; cb++)
                vb[cb] = *(const short8*)&Vt[voff[cb] + kv];
        }
        // exp(kt+1) + write P[(kt+1)&1]; phantom (kt+1==niter) auto-zeroes
        const bool pk = mvn < -1e30f;
        const int kg = k0 + 32 + kb * 16 + l16;
        unsigned short* Pw = Ps[(kt + 1) & 1];
#pragma unroll
        for (int r = 0; r < 4; r++) {
            const int qrow = q0 + rb * 16 + quad * 4 + r;
            float p = 0.f;
            if (kg <= qrow && pk == pq[r]) p = __expf(s[r] * scale);
            lacc[r] += p;
            Pw[(rb * 16 + quad * 4 + r) * 40 + kb * 16 + l16] = f2bf(p);
        }
        asm volatile("s_waitcnt lgkmcnt(0)" ::: "memory");
        __builtin_amdgcn_s_barrier();
        __builtin_amdgcn_sched_barrier(0);
    }

#pragma unroll
    for (int r = 0; r < 4; r++) {
        float v = lacc[r];
        v += __shfl_xor(v, 1);
        v += __shfl_xor(v, 2);
        v += __shfl_xor(v, 4);
        v += __shfl_xor(v, 8);
        if (l16 == 0) atomicAdd(&Ls[rb * 16 + quad * 4 + r], v);
    }
    __syncthreads();

#pragma unroll
    for (int r2 = 0; r2 < 4; r2++) {
#pragma unroll
        for (int r = 0; r < 4; r++) {
            const int qrow = q0 + r2 * 16 + quad * 4 + r;
            const float inv = 1.f / Ls[r2 * 16 + quad * 4 + r];
#pragma unroll
            for (int cb = 0; cb < 4; cb++)
                out[(size_t)(b * 4096 + qrow) * 1024 + dv0 + cb * 16 + l16] = acc[r2][cb][r] * inv;
        }
    }
}

extern "C" void kernel_launch(void* const* d_in, const int* in_sizes, int n_in,
                              void* d_out, int out_size, void* d_ws, size_t ws_size,
                              hipStream_t stream) {
    const float* x  = (const float*)d_in[0];
    const float* Wq = (const float*)d_in[1];
    const float* bq = (const float*)d_in[2];
    const float* Wk = (const float*)d_in[3];
    const float* bk = (const float*)d_in[4];
    const float* Wv = (const float*)d_in[5];
    const float* bv = (const float*)d_in[6];
    const float* mk = (const float*)d_in[7];
    float* out = (float*)d_out;

    char* ws = (char*)d_ws;
    unsigned short* Xb   = (unsigned short*)ws;                      // 32 MB
    unsigned short* Vt   = (unsigned short*)(ws + (33554432));       // 32 MB (1024 x 16384)
    unsigned short* Wt   = (unsigned short*)(ws + (67108864));       // 2.25 MB (1152 x 1024)
    unsigned short* QKb  = (unsigned short*)(ws + (69468160));       // 4 MB  (16384 x 128)
    float*          bfull= (float*)(ws + (73662464));                // 4.5 KB

    conv_x<<<2048, 256, 0, stream>>>(x, Xb);
    transpose_all<<<dim3(16, 18), 256, 0, stream>>>(Wv, Wq, Wk, Wt);
    pack_bias_all<<<2, 576, 0, stream>>>(bv, bq, bk, bfull);

    gemm_fused<<<dim3(128, 9), 256, 0, stream>>>(Xb, Wt, bfull, Vt, QKb);

    attn_fused<<<dim3(4 * 64 * 2), 512, 0, stream>>>(QKb, Vt, mk, out);
}